// Round 1
// 462.699 us; speedup vs baseline: 1.1054x; 1.1054x over previous
//
#include <hip/hip_runtime.h>

// Problem constants
constexpr int D  = 128;
constexpr int M  = 8192;
constexpr int L  = 5;
constexpr int K  = 8;
constexpr int KL = 4;
constexpr int G  = 4096;

constexpr int TB   = 64;            // bucket pad granularity
constexpr int PADL = M + K * TB;    // 8704
constexpr int PADG = G + KL * TB;   // 4352

typedef short bf16x8 __attribute__((ext_vector_type(8)));
typedef float f32x4  __attribute__((ext_vector_type(4)));

__device__ __forceinline__ unsigned short f2bf(float x) {
  union { float f; unsigned int u; } c; c.f = x;
  unsigned int u = c.u + 0x7FFF + ((c.u >> 16) & 1);   // RNE
  return (unsigned short)(u >> 16);
}
__device__ __forceinline__ float bf2f(unsigned short h) {
  union { unsigned int u; float f; } c; c.u = ((unsigned int)h) << 16;
  return c.f;
}

// ---------------------------------------------------------------------------
// Leaf gather: emb fp32 -> hs split-bf16 rows [hi(128) | lo(128)].
__global__ void leaf_gather_kernel(const int* __restrict__ leaf_ids,
                                   const float* __restrict__ emb,
                                   short* __restrict__ hs) {
  int idx = blockIdx.x * 256 + threadIdx.x;      // over M*128
  int n = idx >> 7, d = idx & 127;
  float w = emb[(size_t)leaf_ids[n] * D + d];
  unsigned short hh = f2bf(w);
  hs[n * 256 + d]       = (short)hh;
  hs[n * 256 + 128 + d] = (short)f2bf(w - bf2f(hh));
}

// ---------------------------------------------------------------------------
// Bucket node indices by fid, padded to 64; pad = -1. Valid entries are a
// prefix of each bucket, so every 64-tile AND every 32-tile is fid-uniform.
__global__ void bucket64_kernel(const int* __restrict__ nf_fid,
                                const int* __restrict__ lf_fid,
                                int* __restrict__ orders) {
  int b = blockIdx.x;
  const int* fid; int N, Kf, cap; int* out;
  if (b < L) { fid = nf_fid + b * M; N = M; Kf = K;  cap = PADL; out = orders + b * PADL; }
  else       { fid = lf_fid;         N = G; Kf = KL; cap = PADG; out = orders + L * PADL; }
  __shared__ int cnt[8];
  __shared__ int cur[8];
  int tid = threadIdx.x;
  if (tid < Kf) cnt[tid] = 0;
  __syncthreads();
  for (int i = tid; i < N; i += 256) atomicAdd(&cnt[fid[i]], 1);
  __syncthreads();
  if (tid == 0) {
    int off = 0;
    for (int k = 0; k < Kf; ++k) { cur[k] = off; off += ((cnt[k] + TB - 1) / TB) * TB; }
  }
  __syncthreads();
  for (int i = tid; i < cap; i += 256) out[i] = -1;
  __syncthreads();
  for (int i = tid; i < N; i += 256) {
    int kk = fid[i];
    int pos = atomicAdd(&cur[kk], 1);
    out[pos] = i;
  }
}

// ---------------------------------------------------------------------------
// Weight prep: W[k][KD][F] fp32 -> BT[k][F][2*KD] bf16 as [hi(KD) | lo(KD)].
__global__ void prep_kernel(const float* __restrict__ W1, const float* __restrict__ W2,
                            const float* __restrict__ W3, const float* __restrict__ Wl1,
                            const float* __restrict__ Wl2,
                            short* __restrict__ B1T, short* __restrict__ B2T,
                            short* __restrict__ B3T, short* __restrict__ BL1T,
                            short* __restrict__ BL2T) {
  int b = blockIdx.x;
  const float* W; short* BT; int KD, F;
  if      (b < 4096) { W = W1;  BT = B1T;  KD = 256; F = 512; }
  else if (b < 6144) { W = W2;  BT = B2T;  KD = 512; F = 256; b -= 4096; }
  else if (b < 7168) { W = W3;  BT = B3T;  KD = 256; F = 128; b -= 6144; }
  else if (b < 9216) { W = Wl1; BT = BL1T; KD = 256; F = 512; b -= 7168; }
  else               { W = Wl2; BT = BL2T; KD = 512; F = 128; b -= 9216; }
  int k = b / F, f = b % F;
  for (int d = threadIdx.x; d < KD; d += 256) {
    float w = W[((size_t)k * KD + d) * F + f];
    unsigned short hi = f2bf(w);
    unsigned short lo = f2bf(w - bf2f(hi));
    BT[((size_t)k * F + f) * (2 * KD) + d]      = (short)hi;
    BT[((size_t)k * F + f) * (2 * KD) + KD + d] = (short)lo;
  }
}

// ---------------------------------------------------------------------------
// Grouped GEMM, split-bf16 (logical K' = 3*KH over phys layout [hi|lo]):
//   A' segs {0,1,2} -> phys {hi(0), lo(KH), hi(0)}
//   B' segs {0,1,2} -> phys {hi(0), hi(0), lo(KH)}
// Block: 256 thr, 32 x 128 tile, waves 2x2 (wave tile 16 x 64).
// LDS double-buffered, register prefetch, ONE barrier per 64-chunk.
// FUSED=1: A rows gathered as int4 from split-bf16 hs (no conversion VALU).
// EPI=0: relu(acc+bias) -> split hi/lo bf16 to Aout, coalesced via LDS.
// EPI=1: acc+bias -> fp32 scatter to outp[node], coalesced via LDS.
// EPI=2: acc+bias -> split hi/lo bf16 scatter to Aout[node] (hs rows).
template<int KH, int NN, int EPI, int FUSED>
__global__ __launch_bounds__(256, 3) void mfma_gemm(
    const short* __restrict__ A, const short* __restrict__ hsrc,
    const int* __restrict__ gl, const int* __restrict__ gr,
    const short* __restrict__ BT, const float* __restrict__ bias,
    short* __restrict__ Aout, float* __restrict__ outp,
    const int* __restrict__ order, const int* __restrict__ fid) {
  constexpr int BK    = 64;
  constexpr int NCH   = 3 * KH / BK;      // 12 or 24 (always even)
  constexpr int LDA   = BK + 8;           // 72 shorts -> 2-way bank alias (free)
  constexpr int TROWS = 32;
  __shared__ __align__(16) short As[2][TROWS * LDA];
  __shared__ __align__(16) short Bs[2][128 * LDA];
  __shared__ int nodesS[TROWS], liS[TROWS], riS[TROWS];

  const int tid  = threadIdx.x;
  const int row0 = blockIdx.x * TROWS;
  const int ct   = blockIdx.y;

  if (tid < TROWS) {
    int node = order[row0 + tid];
    nodesS[tid] = node;
    if (FUSED) {
      liS[tid] = node >= 0 ? gl[node] : 0;
      riS[tid] = node >= 0 ? gr[node] : 0;
    }
  }
  __syncthreads();
  if (nodesS[0] < 0) return;              // fully-padded tile
  const int kfn = fid[nodesS[0]];
  const short* __restrict__ Bk = BT + (size_t)kfn * NN * (2 * KH);

  const int lane = tid & 63, wave = tid >> 6;
  const int wr = (wave >> 1) * 16;        // 2x2 waves, wave tile 16x64
  const int wc = wave & 1;
  const int l15 = lane & 15, oct = lane >> 4;

  const int ar = tid >> 3;                // A staging row [0,32)
  const int ag = (tid & 7) * 8;           // A short offset (one int4)
  const int bn = tid >> 1;                // B staging col-row [0,128)
  const int bg = (tid & 1) * 32;          // B short offset

  f32x4 acc[4];
  #pragma unroll
  for (int j = 0; j < 4; ++j) acc[j] = (f32x4)0.f;

  auto loadB_to = [&](int c, int4& r0, int4& r1, int4& r2, int4& r3) {
    int ko = c * BK, seg = ko / KH, wi = ko % KH;
    int pb = (seg == 2) ? KH + wi : wi;
    const int4* p = (const int4*)(Bk + (size_t)(ct * 128 + bn) * (2 * KH) + pb + bg);
    r0 = p[0]; r1 = p[1]; r2 = p[2]; r3 = p[3];
  };
  auto loadA_to = [&](int c, int4& r0) {
    int ko = c * BK, seg = ko / KH, wi = ko % KH;
    int pa = ((seg == 1) ? KH : 0) + wi + ag;      // phys short idx in [0, 2*KH)
    if (FUSED) {
      // A row = [hi_l |hi_r | lo_l | lo_r]; hs row = [hi(128) | lo(128)]
      int s4 = pa >> 7;                            // 0:hi_l 1:hi_r 2:lo_l 3:lo_r
      int node = (s4 & 1) ? riS[ar] : liS[ar];
      if (nodesS[ar] >= 0) {
        r0 = *(const int4*)(hsrc + (size_t)node * 256 + ((s4 >> 1) << 7) + (pa & 127));
      } else {
        r0 = make_int4(0, 0, 0, 0);
      }
    } else {
      r0 = *(const int4*)(A + (size_t)(row0 + ar) * (2 * KH) + pa);
    }
  };
  auto storeA = [&](int b, const int4& r0) {
    *(int4*)&As[b][ar * LDA + ag] = r0;
  };
  auto storeB = [&](int b, const int4& r0, const int4& r1, const int4& r2, const int4& r3) {
    int4* db = (int4*)&Bs[b][bn * LDA + bg];
    db[0] = r0; db[1] = r1; db[2] = r2; db[3] = r3;
  };
  auto compute = [&](int b) {
    __builtin_amdgcn_s_setprio(1);
    #pragma unroll
    for (int s = 0; s < 2; ++s) {
      const int ko = s * 32 + oct * 8;
      bf16x8 afr = *(const bf16x8*)&As[b][(wr + l15) * LDA + ko];
      #pragma unroll
      for (int cf = 0; cf < 4; ++cf) {
        bf16x8 bb = *(const bf16x8*)&Bs[b][(wc * 64 + cf * 16 + l15) * LDA + ko];
        acc[cf] = __builtin_amdgcn_mfma_f32_16x16x32_bf16(afr, bb, acc[cf], 0, 0, 0);
      }
    }
    __builtin_amdgcn_s_setprio(0);
  };

  // ---- main loop: dbuf LDS, 2 register prefetch sets, 1 barrier/chunk
  int4 a0, a1, b00, b01, b02, b03, b10, b11, b12, b13;
  loadA_to(0, a0); loadB_to(0, b00, b01, b02, b03);
  loadA_to(1, a1); loadB_to(1, b10, b11, b12, b13);
  storeA(0, a0); storeB(0, b00, b01, b02, b03);
  __syncthreads();
  for (int c = 0; c < NCH; c += 2) {
    storeA(1, a1); storeB(1, b10, b11, b12, b13);         // chunk c+1 -> buf1
    if (c + 2 < NCH) { loadA_to(c + 2, a0); loadB_to(c + 2, b00, b01, b02, b03); }
    compute(0);                                           // chunk c from buf0
    __syncthreads();
    if (c + 2 < NCH) { storeA(0, a0); storeB(0, b00, b01, b02, b03); }  // c+2 -> buf0
    if (c + 3 < NCH) { loadA_to(c + 3, a1); loadB_to(c + 3, b10, b11, b12, b13); }
    compute(1);                                           // chunk c+1 from buf1
    __syncthreads();
  }

  // ---- Epilogue (coalesced via LDS; Bs is free after the final barrier)
  if (EPI == 0) {
    short* Ls = (short*)&Bs[0][0];           // TROWS*128 shorts = 8 KB
    #pragma unroll
    for (int part = 0; part < 2; ++part) {
      __syncthreads();
      #pragma unroll
      for (int cf = 0; cf < 4; ++cf) {
        int colL = wc * 64 + cf * 16 + l15;
        float bv = bias[kfn * NN + ct * 128 + colL];
        #pragma unroll
        for (int j = 0; j < 4; ++j) {
          int row = wr + oct * 4 + j;
          float v = fmaxf(acc[cf][j] + bv, 0.f);
          unsigned short hh = f2bf(v);
          unsigned short val = (part == 0) ? hh : f2bf(v - bf2f(hh));
          Ls[row * 128 + colL] = (short)val;
        }
      }
      __syncthreads();
      int row = tid >> 3, sg = (tid & 7) * 16;
      const int4* src = (const int4*)&Ls[row * 128 + sg];
      int4* dst = (int4*)&Aout[(size_t)(row0 + row) * (2 * NN) + part * NN + ct * 128 + sg];
      dst[0] = src[0]; dst[1] = src[1];
    }
  } else if (EPI == 1) {
    float* Lf = (float*)&Bs[0][0];           // TROWS*64 floats = 8 KB
    #pragma unroll
    for (int h = 0; h < 2; ++h) {
      __syncthreads();
      if (wc == h) {
        #pragma unroll
        for (int cf = 0; cf < 4; ++cf) {
          int colL = cf * 16 + l15;
          float bv = bias[kfn * 128 + h * 64 + colL];
          #pragma unroll
          for (int j = 0; j < 4; ++j) {
            int row = wr + oct * 4 + j;
            Lf[row * 64 + colL] = acc[cf][j] + bv;
          }
        }
      }
      __syncthreads();
      int row = tid >> 3, off = (tid & 7) * 8;
      int node = nodesS[row];
      if (node >= 0) {
        const float4* src = (const float4*)&Lf[row * 64 + off];
        float4* dst = (float4*)&outp[(size_t)node * 128 + h * 64 + off];
        dst[0] = src[0]; dst[1] = src[1];
      }
    }
  } else {                                   // EPI == 2: split-bf16 hs scatter
    short* Ls = (short*)&Bs[0][0];           // TROWS*256 shorts = 16 KB
    #pragma unroll
    for (int cf = 0; cf < 4; ++cf) {
      int colL = wc * 64 + cf * 16 + l15;
      float bv = bias[kfn * 128 + colL];
      #pragma unroll
      for (int j = 0; j < 4; ++j) {
        int row = wr + oct * 4 + j;
        float v = acc[cf][j] + bv;
        unsigned short hh = f2bf(v);
        Ls[row * 256 + colL]       = (short)hh;
        Ls[row * 256 + 128 + colL] = (short)f2bf(v - bf2f(hh));
      }
    }
    __syncthreads();
    int row = tid >> 3, sg = (tid & 7) * 32;
    int node = nodesS[row];
    if (node >= 0) {
      const int4* src = (const int4*)&Ls[row * 256 + sg];
      int4* dst = (int4*)&Aout[(size_t)node * 256 + sg];
      dst[0] = src[0]; dst[1] = src[1]; dst[2] = src[2]; dst[3] = src[3];
    }
  }
}

// ---------------------------------------------------------------------------
extern "C" void kernel_launch(void* const* d_in, const int* in_sizes, int n_in,
                              void* d_out, int out_size, void* d_ws, size_t ws_size,
                              hipStream_t stream) {
  const int*   leaf_ids  = (const int*)d_in[0];
  const int*   left_idx  = (const int*)d_in[1];
  const int*   right_idx = (const int*)d_in[2];
  const int*   nf_fid    = (const int*)d_in[3];
  const int*   gt_left   = (const int*)d_in[4];
  const int*   gt_right  = (const int*)d_in[5];
  const int*   lf_fid    = (const int*)d_in[6];
  const float* emb       = (const float*)d_in[7];
  const float* W1 = (const float*)d_in[8];
  const float* b1 = (const float*)d_in[9];
  const float* W2 = (const float*)d_in[10];
  const float* b2 = (const float*)d_in[11];
  const float* W3 = (const float*)d_in[12];
  const float* b3 = (const float*)d_in[13];
  const float* Wl1 = (const float*)d_in[14];
  const float* bl1 = (const float*)d_in[15];
  const float* Wl2 = (const float*)d_in[16];
  const float* bl2 = (const float*)d_in[17];
  float* out = (float*)d_out;

  // workspace layout (~54 MB)
  const size_t SZ_H    = (size_t)M * 256 * 2;          // split-bf16 h rows
  const size_t SZ_A1   = (size_t)PADL * 1024 * 2;
  const size_t SZ_A2   = (size_t)PADL * 512 * 2;
  const size_t SZ_B1T  = (size_t)8 * 512 * 512 * 2;
  const size_t SZ_B2T  = (size_t)8 * 256 * 1024 * 2;
  const size_t SZ_B3T  = (size_t)8 * 128 * 512 * 2;
  const size_t SZ_BL1T = (size_t)4 * 512 * 512 * 2;
  const size_t SZ_BL2T = (size_t)4 * 128 * 1024 * 2;

  char* p = (char*)d_ws;
  short* hsA  = (short*)p;  p += SZ_H;
  short* hsB  = (short*)p;  p += SZ_H;
  short* a1s  = (short*)p;  p += SZ_A1;
  short* a2s  = (short*)p;  p += SZ_A2;
  short* B1T  = (short*)p;  p += SZ_B1T;
  short* B2T  = (short*)p;  p += SZ_B2T;
  short* B3T  = (short*)p;  p += SZ_B3T;
  short* BL1T = (short*)p;  p += SZ_BL1T;
  short* BL2T = (short*)p;  p += SZ_BL2T;
  int*   orders = (int*)p;

  leaf_gather_kernel<<<(M * D) / 256, 256, 0, stream>>>(leaf_ids, emb, hsA);
  bucket64_kernel<<<L + 1, 256, 0, stream>>>(nf_fid, lf_fid, orders);
  prep_kernel<<<9728, 256, 0, stream>>>(W1, W2, W3, Wl1, Wl2,
                                        B1T, B2T, B3T, BL1T, BL2T);

  short* hin = hsA;
  short* hout = hsB;
  for (int l = 0; l < L; ++l) {
    const int* ord = orders + l * PADL;
    const int* fidl = nf_fid + l * M;
    // GEMM1: fused int4 gather from hs, K'=3*256, N=512, relu+split (272x4)
    mfma_gemm<256, 512, 0, 1><<<dim3(PADL / 32, 4), 256, 0, stream>>>(
        nullptr, hin, left_idx + l * M, right_idx + l * M,
        B1T, b1, a1s, nullptr, ord, fidl);
    // GEMM2: K'=3*512, N=256, relu+split                           (272x2)
    mfma_gemm<512, 256, 0, 0><<<dim3(PADL / 32, 2), 256, 0, stream>>>(
        a1s, nullptr, nullptr, nullptr,
        B2T, b2, a2s, nullptr, ord, fidl);
    // GEMM3: K'=3*256, N=128, bias + split-bf16 hs scatter         (272)
    mfma_gemm<256, 128, 2, 0><<<dim3(PADL / 32, 1), 256, 0, stream>>>(
        a2s, nullptr, nullptr, nullptr,
        B3T, b3, hout, nullptr, ord, fidl);
    short* t = hin; hin = hout; hout = t;
  }
  const int* ordG = orders + L * PADL;
  // Logic GEMM1: fused int4 gather from final hs                   (136x4)
  mfma_gemm<256, 512, 0, 1><<<dim3(PADG / 32, 4), 256, 0, stream>>>(
      nullptr, hin, gt_left, gt_right,
      BL1T, bl1, a1s, nullptr, ordG, lf_fid);
  // Logic GEMM2: K'=3*512, N=128, bias+scatter fp32 to d_out       (136)
  mfma_gemm<512, 128, 1, 0><<<dim3(PADG / 32, 1), 256, 0, stream>>>(
      a1s, nullptr, nullptr, nullptr,
      BL2T, bl2, nullptr, out, ordG, lf_fid);
}

// Round 2
// 462.252 us; speedup vs baseline: 1.1065x; 1.0010x over previous
//
#include <hip/hip_runtime.h>

// Problem constants
constexpr int D  = 128;
constexpr int M  = 8192;
constexpr int L  = 5;
constexpr int K  = 8;
constexpr int KL = 4;
constexpr int G  = 4096;

constexpr int TB   = 64;            // bucket pad granularity
constexpr int PADL = M + K * TB;    // 8704
constexpr int PADG = G + KL * TB;   // 4352

typedef short bf16x8 __attribute__((ext_vector_type(8)));
typedef float f32x4  __attribute__((ext_vector_type(4)));

__device__ __forceinline__ unsigned short f2bf(float x) {
  union { float f; unsigned int u; } c; c.f = x;
  unsigned int u = c.u + 0x7FFF + ((c.u >> 16) & 1);   // RNE
  return (unsigned short)(u >> 16);
}
__device__ __forceinline__ float bf2f(unsigned short h) {
  union { unsigned int u; float f; } c; c.u = ((unsigned int)h) << 16;
  return c.f;
}

// Bijective XCD-chunking swizzle (m204): contiguous blockIdx.x runs land on
// the same XCD so same-(fid,ct) blocks share one L2's copy of the B-slice.
__device__ __forceinline__ int xcd_swizzle(int b, int n) {
  int q = n >> 3, r = n & 7, xcd = b & 7, off = b >> 3;
  return (xcd < r ? xcd * (q + 1) : r * (q + 1) + (xcd - r) * q) + off;
}

// ---------------------------------------------------------------------------
// Leaf gather: emb fp32 -> hs split-bf16 rows [hi(128) | lo(128)].
__global__ void leaf_gather_kernel(const int* __restrict__ leaf_ids,
                                   const float* __restrict__ emb,
                                   short* __restrict__ hs) {
  int idx = blockIdx.x * 256 + threadIdx.x;      // over M*128
  int n = idx >> 7, d = idx & 127;
  float w = emb[(size_t)leaf_ids[n] * D + d];
  unsigned short hh = f2bf(w);
  hs[n * 256 + d]       = (short)hh;
  hs[n * 256 + 128 + d] = (short)f2bf(w - bf2f(hh));
}

// ---------------------------------------------------------------------------
// Bucket node indices by fid, padded to 64; pad = -1. Valid entries are a
// prefix of each bucket, so every 64-tile AND every 32-tile is fid-uniform.
__global__ void bucket64_kernel(const int* __restrict__ nf_fid,
                                const int* __restrict__ lf_fid,
                                int* __restrict__ orders) {
  int b = blockIdx.x;
  const int* fid; int N, Kf, cap; int* out;
  if (b < L) { fid = nf_fid + b * M; N = M; Kf = K;  cap = PADL; out = orders + b * PADL; }
  else       { fid = lf_fid;         N = G; Kf = KL; cap = PADG; out = orders + L * PADL; }
  __shared__ int cnt[8];
  __shared__ int cur[8];
  int tid = threadIdx.x;
  if (tid < Kf) cnt[tid] = 0;
  __syncthreads();
  for (int i = tid; i < N; i += 256) atomicAdd(&cnt[fid[i]], 1);
  __syncthreads();
  if (tid == 0) {
    int off = 0;
    for (int k = 0; k < Kf; ++k) { cur[k] = off; off += ((cnt[k] + TB - 1) / TB) * TB; }
  }
  __syncthreads();
  for (int i = tid; i < cap; i += 256) out[i] = -1;
  __syncthreads();
  for (int i = tid; i < N; i += 256) {
    int kk = fid[i];
    int pos = atomicAdd(&cur[kk], 1);
    out[pos] = i;
  }
}

// ---------------------------------------------------------------------------
// Weight prep: W[k][KD][F] fp32 -> BT[k][F][2*KD] bf16 as [hi(KD) | lo(KD)].
__global__ void prep_kernel(const float* __restrict__ W1, const float* __restrict__ W2,
                            const float* __restrict__ W3, const float* __restrict__ Wl1,
                            const float* __restrict__ Wl2,
                            short* __restrict__ B1T, short* __restrict__ B2T,
                            short* __restrict__ B3T, short* __restrict__ BL1T,
                            short* __restrict__ BL2T) {
  int b = blockIdx.x;
  const float* W; short* BT; int KD, F;
  if      (b < 4096) { W = W1;  BT = B1T;  KD = 256; F = 512; }
  else if (b < 6144) { W = W2;  BT = B2T;  KD = 512; F = 256; b -= 4096; }
  else if (b < 7168) { W = W3;  BT = B3T;  KD = 256; F = 128; b -= 6144; }
  else if (b < 9216) { W = Wl1; BT = BL1T; KD = 256; F = 512; b -= 7168; }
  else               { W = Wl2; BT = BL2T; KD = 512; F = 128; b -= 9216; }
  int k = b / F, f = b % F;
  for (int d = threadIdx.x; d < KD; d += 256) {
    float w = W[((size_t)k * KD + d) * F + f];
    unsigned short hi = f2bf(w);
    unsigned short lo = f2bf(w - bf2f(hi));
    BT[((size_t)k * F + f) * (2 * KD) + d]      = (short)hi;
    BT[((size_t)k * F + f) * (2 * KD) + KD + d] = (short)lo;
  }
}

// ---------------------------------------------------------------------------
// Grouped GEMM, split-bf16 (logical K' = 3*KH over phys layout [hi|lo]):
//   A' segs {0,1,2} -> phys {hi(0), lo(KH), hi(0)}
//   B' segs {0,1,2} -> phys {hi(0), hi(0), lo(KH)}
// Block: 256 thr, TROWS x 128 tile, waves 2x2 (wave tile TROWS/2 x 64).
// LDS double-buffered, register prefetch, ONE barrier per 64-chunk.
// FUSED=1: A rows gathered as int4 from split-bf16 hs (no conversion VALU).
// EPI=0: relu(acc+bias) -> split hi/lo bf16 to Aout, coalesced via LDS.
// EPI=1: acc+bias -> fp32 scatter to outp[node], coalesced via LDS.
// EPI=2: acc+bias -> split hi/lo bf16 scatter to Aout[node] (hs rows).
template<int KH, int NN, int EPI, int FUSED, int TROWS>
__global__ __launch_bounds__(256, TROWS == 64 ? 2 : 3) void mfma_gemm(
    const short* __restrict__ A, const short* __restrict__ hsrc,
    const int* __restrict__ gl, const int* __restrict__ gr,
    const short* __restrict__ BT, const float* __restrict__ bias,
    short* __restrict__ Aout, float* __restrict__ outp,
    const int* __restrict__ order, const int* __restrict__ fid) {
  constexpr int BK    = 64;
  constexpr int NCH   = 3 * KH / BK;      // 12 or 24 (always even)
  constexpr int LDA   = BK + 8;           // 72 shorts -> 2-way bank alias (free)
  constexpr int RF    = TROWS / 32;       // row frags per wave: 2 or 1
  constexpr int TPR   = 256 / TROWS;      // A-staging threads per row: 4 or 8
  __shared__ __align__(16) short As[2][TROWS * LDA];
  __shared__ __align__(16) short Bs[2][128 * LDA];
  __shared__ int nodesS[TROWS], liS[TROWS], riS[TROWS];

  const int tid  = threadIdx.x;
  const int bx   = xcd_swizzle(blockIdx.x, gridDim.x);
  const int row0 = bx * TROWS;
  const int ct   = blockIdx.y;

  if (tid < TROWS) {
    int node = order[row0 + tid];
    nodesS[tid] = node;
    if (FUSED) {
      liS[tid] = node >= 0 ? gl[node] : 0;
      riS[tid] = node >= 0 ? gr[node] : 0;
    }
  }
  __syncthreads();
  if (nodesS[0] < 0) return;              // fully-padded tile
  const int kfn = fid[nodesS[0]];
  const short* __restrict__ Bk = BT + (size_t)kfn * NN * (2 * KH);

  const int lane = tid & 63, wave = tid >> 6;
  const int wr = (wave >> 1) * (TROWS / 2);   // 2x2 waves
  const int wc = wave & 1;
  const int l15 = lane & 15, oct = lane >> 4;

  const int ar = tid / TPR;                   // A staging row [0,TROWS)
  const int ag = (tid % TPR) * (BK / TPR);    // A short offset (16 or 8)
  const int bn = tid >> 1;                    // B staging col-row [0,128)
  const int bg = (tid & 1) * 32;              // B short offset

  f32x4 acc[RF][4];
  #pragma unroll
  for (int i = 0; i < RF; ++i)
    #pragma unroll
    for (int j = 0; j < 4; ++j) acc[i][j] = (f32x4)0.f;

  auto loadB_to = [&](int c, int4& r0, int4& r1, int4& r2, int4& r3) {
    int ko = c * BK, seg = ko / KH, wi = ko % KH;
    int pb = (seg == 2) ? KH + wi : wi;
    const int4* p = (const int4*)(Bk + (size_t)(ct * 128 + bn) * (2 * KH) + pb + bg);
    r0 = p[0]; r1 = p[1]; r2 = p[2]; r3 = p[3];
  };
  auto loadA_to = [&](int c, int4& r0, int4& r1) {
    int ko = c * BK, seg = ko / KH, wi = ko % KH;
    int pa = ((seg == 1) ? KH : 0) + wi + ag;      // phys short idx in [0, 2*KH)
    if (FUSED) {
      // A row = [hi_l |hi_r | lo_l | lo_r]; hs row = [hi(128) | lo(128)]
      // ag is a multiple of 16 and BK/TPR<=16, so the 8/16 shorts stay in one
      // 128-short run -> single s4 selector for both int4s.
      int s4 = pa >> 7;                            // 0:hi_l 1:hi_r 2:lo_l 3:lo_r
      int node = (s4 & 1) ? riS[ar] : liS[ar];
      if (nodesS[ar] >= 0) {
        const int4* p = (const int4*)(hsrc + (size_t)node * 256 + ((s4 >> 1) << 7) + (pa & 127));
        r0 = p[0];
        if (TPR == 4) r1 = p[1];
      } else {
        r0 = make_int4(0, 0, 0, 0);
        if (TPR == 4) r1 = make_int4(0, 0, 0, 0);
      }
    } else {
      const int4* p = (const int4*)(A + (size_t)(row0 + ar) * (2 * KH) + pa);
      r0 = p[0];
      if (TPR == 4) r1 = p[1];
    }
  };
  auto storeA = [&](int b, const int4& r0, const int4& r1) {
    int4* d4 = (int4*)&As[b][ar * LDA + ag];
    d4[0] = r0;
    if (TPR == 4) d4[1] = r1;
  };
  auto storeB = [&](int b, const int4& r0, const int4& r1, const int4& r2, const int4& r3) {
    int4* db = (int4*)&Bs[b][bn * LDA + bg];
    db[0] = r0; db[1] = r1; db[2] = r2; db[3] = r3;
  };
  auto compute = [&](int b) {
    __builtin_amdgcn_s_setprio(1);
    #pragma unroll
    for (int s = 0; s < 2; ++s) {
      const int ko = s * 32 + oct * 8;
      bf16x8 afr[RF];
      #pragma unroll
      for (int rf = 0; rf < RF; ++rf)
        afr[rf] = *(const bf16x8*)&As[b][(wr + rf * 16 + l15) * LDA + ko];
      #pragma unroll
      for (int cf = 0; cf < 4; ++cf) {
        bf16x8 bb = *(const bf16x8*)&Bs[b][(wc * 64 + cf * 16 + l15) * LDA + ko];
        #pragma unroll
        for (int rf = 0; rf < RF; ++rf)
          acc[rf][cf] = __builtin_amdgcn_mfma_f32_16x16x32_bf16(afr[rf], bb, acc[rf][cf], 0, 0, 0);
      }
    }
    __builtin_amdgcn_s_setprio(0);
  };

  // ---- main loop: dbuf LDS, 2 register prefetch sets, 1 barrier/chunk
  int4 a00, a01, a10, a11;
  int4 b00, b01, b02, b03, b10, b11, b12, b13;
  loadA_to(0, a00, a01); loadB_to(0, b00, b01, b02, b03);
  loadA_to(1, a10, a11); loadB_to(1, b10, b11, b12, b13);
  storeA(0, a00, a01); storeB(0, b00, b01, b02, b03);
  __syncthreads();
  for (int c = 0; c < NCH; c += 2) {
    storeA(1, a10, a11); storeB(1, b10, b11, b12, b13);   // chunk c+1 -> buf1
    if (c + 2 < NCH) { loadA_to(c + 2, a00, a01); loadB_to(c + 2, b00, b01, b02, b03); }
    compute(0);                                           // chunk c from buf0
    __syncthreads();
    if (c + 2 < NCH) { storeA(0, a00, a01); storeB(0, b00, b01, b02, b03); }  // c+2 -> buf0
    if (c + 3 < NCH) { loadA_to(c + 3, a10, a11); loadB_to(c + 3, b10, b11, b12, b13); }
    compute(1);                                           // chunk c+1 from buf1
    __syncthreads();
  }

  // ---- Epilogue (coalesced via LDS; Bs is free after the final barrier)
  if (EPI == 0) {
    short* Ls = (short*)&Bs[0][0];           // TROWS*128 shorts (8 or 16 KB)
    #pragma unroll
    for (int part = 0; part < 2; ++part) {
      __syncthreads();
      #pragma unroll
      for (int rf = 0; rf < RF; ++rf)
        #pragma unroll
        for (int cf = 0; cf < 4; ++cf) {
          int colL = wc * 64 + cf * 16 + l15;
          float bv = bias[kfn * NN + ct * 128 + colL];
          #pragma unroll
          for (int j = 0; j < 4; ++j) {
            int row = wr + rf * 16 + oct * 4 + j;
            float v = fmaxf(acc[rf][cf][j] + bv, 0.f);
            unsigned short hh = f2bf(v);
            unsigned short val = (part == 0) ? hh : f2bf(v - bf2f(hh));
            Ls[row * 128 + colL] = (short)val;
          }
        }
      __syncthreads();
      constexpr int SPT = TROWS / 2;         // shorts per thread (32 or 16)
      constexpr int TPW = 128 / SPT;         // threads per row (4 or 8)
      int row = tid / TPW, sg = (tid % TPW) * SPT;
      const int4* src = (const int4*)&Ls[row * 128 + sg];
      int4* dst = (int4*)&Aout[(size_t)(row0 + row) * (2 * NN) + part * NN + ct * 128 + sg];
      #pragma unroll
      for (int q = 0; q < SPT / 8; ++q) dst[q] = src[q];
    }
  } else if (EPI == 1) {
    float* Lf = (float*)&Bs[0][0];           // TROWS*64 floats
    #pragma unroll
    for (int h = 0; h < 2; ++h) {
      __syncthreads();
      if (wc == h) {
        #pragma unroll
        for (int rf = 0; rf < RF; ++rf)
          #pragma unroll
          for (int cf = 0; cf < 4; ++cf) {
            int colL = cf * 16 + l15;
            float bv = bias[kfn * 128 + h * 64 + colL];
            #pragma unroll
            for (int j = 0; j < 4; ++j) {
              int row = wr + rf * 16 + oct * 4 + j;
              Lf[row * 64 + colL] = acc[rf][cf][j] + bv;
            }
          }
      }
      __syncthreads();
      constexpr int FPT = TROWS / 4;         // floats per thread (16 or 8)
      constexpr int TPW = 64 / FPT;          // threads per row (4 or 8)
      int row = tid / TPW, off = (tid % TPW) * FPT;
      int node = nodesS[row];
      if (node >= 0) {
        const float4* src = (const float4*)&Lf[row * 64 + off];
        float4* dst = (float4*)&outp[(size_t)node * 128 + h * 64 + off];
        #pragma unroll
        for (int q = 0; q < FPT / 4; ++q) dst[q] = src[q];
      }
    }
  } else {                                   // EPI == 2: split-bf16 hs scatter
    short* Ls = (short*)&Bs[0][0];           // TROWS*256 shorts
    #pragma unroll
    for (int rf = 0; rf < RF; ++rf)
      #pragma unroll
      for (int cf = 0; cf < 4; ++cf) {
        int colL = wc * 64 + cf * 16 + l15;
        float bv = bias[kfn * 128 + colL];
        #pragma unroll
        for (int j = 0; j < 4; ++j) {
          int row = wr + rf * 16 + oct * 4 + j;
          float v = acc[rf][cf][j] + bv;
          unsigned short hh = f2bf(v);
          Ls[row * 256 + colL]       = (short)hh;
          Ls[row * 256 + 128 + colL] = (short)f2bf(v - bf2f(hh));
        }
      }
    __syncthreads();
    constexpr int SPT = 256 * TROWS / 256;   // shorts per thread (= TROWS)
    constexpr int TPW = 256 / SPT;           // threads per row
    int row = tid / TPW, sg = (tid % TPW) * SPT;
    int node = nodesS[row];
    if (node >= 0) {
      const int4* src = (const int4*)&Ls[row * 256 + sg];
      int4* dst = (int4*)&Aout[(size_t)node * 256 + sg];
      #pragma unroll
      for (int q = 0; q < SPT / 8; ++q) dst[q] = src[q];
    }
  }
}

// ---------------------------------------------------------------------------
extern "C" void kernel_launch(void* const* d_in, const int* in_sizes, int n_in,
                              void* d_out, int out_size, void* d_ws, size_t ws_size,
                              hipStream_t stream) {
  const int*   leaf_ids  = (const int*)d_in[0];
  const int*   left_idx  = (const int*)d_in[1];
  const int*   right_idx = (const int*)d_in[2];
  const int*   nf_fid    = (const int*)d_in[3];
  const int*   gt_left   = (const int*)d_in[4];
  const int*   gt_right  = (const int*)d_in[5];
  const int*   lf_fid    = (const int*)d_in[6];
  const float* emb       = (const float*)d_in[7];
  const float* W1 = (const float*)d_in[8];
  const float* b1 = (const float*)d_in[9];
  const float* W2 = (const float*)d_in[10];
  const float* b2 = (const float*)d_in[11];
  const float* W3 = (const float*)d_in[12];
  const float* b3 = (const float*)d_in[13];
  const float* Wl1 = (const float*)d_in[14];
  const float* bl1 = (const float*)d_in[15];
  const float* Wl2 = (const float*)d_in[16];
  const float* bl2 = (const float*)d_in[17];
  float* out = (float*)d_out;

  // workspace layout (~54 MB)
  const size_t SZ_H    = (size_t)M * 256 * 2;          // split-bf16 h rows
  const size_t SZ_A1   = (size_t)PADL * 1024 * 2;
  const size_t SZ_A2   = (size_t)PADL * 512 * 2;
  const size_t SZ_B1T  = (size_t)8 * 512 * 512 * 2;
  const size_t SZ_B2T  = (size_t)8 * 256 * 1024 * 2;
  const size_t SZ_B3T  = (size_t)8 * 128 * 512 * 2;
  const size_t SZ_BL1T = (size_t)4 * 512 * 512 * 2;
  const size_t SZ_BL2T = (size_t)4 * 128 * 1024 * 2;

  char* p = (char*)d_ws;
  short* hsA  = (short*)p;  p += SZ_H;
  short* hsB  = (short*)p;  p += SZ_H;
  short* a1s  = (short*)p;  p += SZ_A1;
  short* a2s  = (short*)p;  p += SZ_A2;
  short* B1T  = (short*)p;  p += SZ_B1T;
  short* B2T  = (short*)p;  p += SZ_B2T;
  short* B3T  = (short*)p;  p += SZ_B3T;
  short* BL1T = (short*)p;  p += SZ_BL1T;
  short* BL2T = (short*)p;  p += SZ_BL2T;
  int*   orders = (int*)p;

  leaf_gather_kernel<<<(M * D) / 256, 256, 0, stream>>>(leaf_ids, emb, hsA);
  bucket64_kernel<<<L + 1, 256, 0, stream>>>(nf_fid, lf_fid, orders);
  prep_kernel<<<9728, 256, 0, stream>>>(W1, W2, W3, Wl1, Wl2,
                                        B1T, B2T, B3T, BL1T, BL2T);

  short* hin = hsA;
  short* hout = hsB;
  for (int l = 0; l < L; ++l) {
    const int* ord = orders + l * PADL;
    const int* fidl = nf_fid + l * M;
    // GEMM1: fused int4 gather, 64x128 tiles, K'=3*256, N=512     (136x4)
    mfma_gemm<256, 512, 0, 1, 64><<<dim3(PADL / 64, 4), 256, 0, stream>>>(
        nullptr, hin, left_idx + l * M, right_idx + l * M,
        B1T, b1, a1s, nullptr, ord, fidl);
    // GEMM2: 64x128 tiles, K'=3*512, N=256                        (136x2)
    mfma_gemm<512, 256, 0, 0, 64><<<dim3(PADL / 64, 2), 256, 0, stream>>>(
        a1s, nullptr, nullptr, nullptr,
        B2T, b2, a2s, nullptr, ord, fidl);
    // GEMM3: 32x128 tiles, K'=3*256, N=128, split-bf16 hs scatter (272)
    mfma_gemm<256, 128, 2, 0, 32><<<dim3(PADL / 32, 1), 256, 0, stream>>>(
        a2s, nullptr, nullptr, nullptr,
        B3T, b3, hout, nullptr, ord, fidl);
    short* t = hin; hin = hout; hout = t;
  }
  const int* ordG = orders + L * PADL;
  // Logic GEMM1: fused int4 gather, 64x128 tiles                  (68x4)
  mfma_gemm<256, 512, 0, 1, 64><<<dim3(PADG / 64, 4), 256, 0, stream>>>(
      nullptr, hin, gt_left, gt_right,
      BL1T, bl1, a1s, nullptr, ordG, lf_fid);
  // Logic GEMM2: 32x128 tiles, K'=3*512, N=128, fp32 to d_out     (136)
  mfma_gemm<512, 128, 1, 0, 32><<<dim3(PADG / 32, 1), 256, 0, stream>>>(
      a1s, nullptr, nullptr, nullptr,
      BL2T, bl2, nullptr, out, ordG, lf_fid);
}